// Round 1
// baseline (18510.509 us; speedup 1.0000x reference)
//
#include <hip/hip_runtime.h>
#include <hip/hip_cooperative_groups.h>
#include <math.h>

namespace cg = cooperative_groups;

#define NTOK 50257
#define NPC  225
#define NCLS 224
#define NH   1024
#define G4   4096
#define TSTEPS 128
#define BB   64
#define NN   8192

__device__ __forceinline__ float sigmf(float x){ return 1.0f/(1.0f+expf(-x)); }

// ---------------- embedding gather: X[n][:] = emb_W[ids[n]][:] ----------------
__global__ void k_embed(const int* __restrict__ ids, const float* __restrict__ embW,
                        float* __restrict__ X){
  int n = blockIdx.x;
  int t = threadIdx.x;
  const float4* s = (const float4*)(embW + (size_t)ids[n]*NH);
  float4* d = (float4*)(X + (size_t)n*NH);
  d[t] = s[t];
}

// ---------------- C[M=4096][Nd] = A[M][1024] * B[Nd][1024]^T + (bi[m]+bh[m]) ----------------
// C written m-major (transposed gates) so the recurrence reads coalesced along n.
__global__ __launch_bounds__(256) void k_gemm_nt(
    const float* __restrict__ A, const float* __restrict__ B,
    const float* __restrict__ bi, const float* __restrict__ bh,
    float* __restrict__ C, int Nd)
{
  __shared__ float As[32][68];
  __shared__ float Bs[32][68];
  int m0 = blockIdx.x*64, n0 = blockIdx.y*64;
  int t = threadIdx.x;
  int tm = (t&15)*4, tn = (t>>4)*4;
  int lr = t>>3, lk = (t&7)*4;
  float acc[4][4] = {{0.f}};
  for (int k0=0;k0<NH;k0+=32){
    float4 a0 = *(const float4*)(A + (size_t)(m0+lr)*NH + k0+lk);
    float4 a1 = *(const float4*)(A + (size_t)(m0+lr+32)*NH + k0+lk);
    float4 b0 = *(const float4*)(B + (size_t)(n0+lr)*NH + k0+lk);
    float4 b1 = *(const float4*)(B + (size_t)(n0+lr+32)*NH + k0+lk);
    __syncthreads();
    As[lk+0][lr]=a0.x; As[lk+1][lr]=a0.y; As[lk+2][lr]=a0.z; As[lk+3][lr]=a0.w;
    As[lk+0][lr+32]=a1.x; As[lk+1][lr+32]=a1.y; As[lk+2][lr+32]=a1.z; As[lk+3][lr+32]=a1.w;
    Bs[lk+0][lr]=b0.x; Bs[lk+1][lr]=b0.y; Bs[lk+2][lr]=b0.z; Bs[lk+3][lr]=b0.w;
    Bs[lk+0][lr+32]=b1.x; Bs[lk+1][lr+32]=b1.y; Bs[lk+2][lr+32]=b1.z; Bs[lk+3][lr+32]=b1.w;
    __syncthreads();
    #pragma unroll 8
    for (int kk=0;kk<32;kk++){
      float4 av = *(const float4*)&As[kk][tm];
      float4 bv = *(const float4*)&Bs[kk][tn];
      acc[0][0] += av.x*bv.x; acc[0][1] += av.x*bv.y; acc[0][2] += av.x*bv.z; acc[0][3] += av.x*bv.w;
      acc[1][0] += av.y*bv.x; acc[1][1] += av.y*bv.y; acc[1][2] += av.y*bv.z; acc[1][3] += av.y*bv.w;
      acc[2][0] += av.z*bv.x; acc[2][1] += av.z*bv.y; acc[2][2] += av.z*bv.z; acc[2][3] += av.z*bv.w;
      acc[3][0] += av.w*bv.x; acc[3][1] += av.w*bv.y; acc[3][2] += av.w*bv.z; acc[3][3] += av.w*bv.w;
    }
  }
  #pragma unroll
  for (int i=0;i<4;i++){
    int m = m0+tm+i;
    float bias = bi[m]+bh[m];
    float4 o = make_float4(acc[i][0]+bias, acc[i][1]+bias, acc[i][2]+bias, acc[i][3]+bias);
    *(float4*)(C + (size_t)m*Nd + n0+tn) = o;
  }
}

// ---------------- cooperative LSTM recurrence for one layer ----------------
// 256 blocks; block jj owns hidden cols [jj*4, jj*4+4) and their 16 W_hh rows in LDS.
__global__ __launch_bounds__(256,1) void k_rec(
    const float* __restrict__ GT, const float* __restrict__ Wh,
    const float* __restrict__ h0, const float* __restrict__ c0,
    float* __restrict__ hb, float* __restrict__ Y,
    float* __restrict__ hN, float* __restrict__ cN)
{
  cg::grid_group grid = cg::this_grid();
  __shared__ float wlds[16][NH];
  __shared__ float glds[64][17];
  int jj = blockIdx.x, t = threadIdx.x;
  for (int rr=0;rr<16;rr++){
    int grow = (rr>>2)*NH + jj*4 + (rr&3);
    *(float4*)&wlds[rr][t*4] = *(const float4*)(Wh + (size_t)grow*NH + t*4);
  }
  int b = t&63, w = t>>6;
  int hc = jj*4 + w;
  float creg = c0[b*NH + hc];
  hb[b*NH + hc] = h0[b*NH + hc];     // state buffer 0
  grid.sync();
  const float* wp0 = &wlds[w*4+0][0];
  const float* wp1 = &wlds[w*4+1][0];
  const float* wp2 = &wlds[w*4+2][0];
  const float* wp3 = &wlds[w*4+3][0];
  for (int st=0; st<TSTEPS; st++){
    const float* hcur = hb + (size_t)(st&1)*BB*NH;
    float*       hnxt = hb + (size_t)((st+1)&1)*BB*NH;
    int n = st*BB + b;
    size_t gbase = (size_t)(w*NH + jj*4)*NN + n;
    float a0 = GT[gbase];
    float a1 = GT[gbase + (size_t)NN];
    float a2 = GT[gbase + 2*(size_t)NN];
    float a3 = GT[gbase + 3*(size_t)NN];
    const float* hrow = hcur + b*NH;
    #pragma unroll 4
    for (int k=0;k<NH;k+=4){
      float4 h4 = *(const float4*)(hrow+k);
      float4 q0 = *(const float4*)(wp0+k);
      float4 q1 = *(const float4*)(wp1+k);
      float4 q2 = *(const float4*)(wp2+k);
      float4 q3 = *(const float4*)(wp3+k);
      a0 += h4.x*q0.x + h4.y*q0.y + h4.z*q0.z + h4.w*q0.w;
      a1 += h4.x*q1.x + h4.y*q1.y + h4.z*q1.z + h4.w*q1.w;
      a2 += h4.x*q2.x + h4.y*q2.y + h4.z*q2.z + h4.w*q2.w;
      a3 += h4.x*q3.x + h4.y*q3.y + h4.z*q3.z + h4.w*q3.w;
    }
    glds[b][w*4+0]=a0; glds[b][w*4+1]=a1; glds[b][w*4+2]=a2; glds[b][w*4+3]=a3;
    __syncthreads();
    float gi = glds[b][0*4+w];
    float gf = glds[b][1*4+w];
    float gg = glds[b][2*4+w];
    float go = glds[b][3*4+w];
    float cnew = sigmf(gf)*creg + sigmf(gi)*tanhf(gg);
    creg = cnew;
    float hv = sigmf(go)*tanhf(cnew);
    hnxt[b*NH + hc] = hv;
    Y[(size_t)n*NH + hc] = hv;
    if (st == TSTEPS-1){ hN[b*NH+hc] = hv; cN[b*NH+hc] = creg; }
    grid.sync();
  }
}

// ---------------- top logits: C[NN][224] = X[NN][1024] @ W[1024][224] + b ----------------
__global__ __launch_bounds__(256) void k_gemm_top(
    const float* __restrict__ X, const float* __restrict__ W,
    const float* __restrict__ bias, float* __restrict__ C)
{
  __shared__ float Xs[32][68];
  __shared__ float Ws[32][36];
  int n0 = blockIdx.x*64, c0 = blockIdx.y*32;
  int t = threadIdx.x;
  int tm = (t&15)*4;   // n offset
  int tn = (t>>4)*2;   // c offset
  int lr = t>>3, lk = (t&7)*4;
  float acc[4][2] = {{0.f}};
  for (int k0=0;k0<NH;k0+=32){
    float4 x0 = *(const float4*)(X + (size_t)(n0+lr)*NH + k0+lk);
    float4 x1 = *(const float4*)(X + (size_t)(n0+lr+32)*NH + k0+lk);
    float4 wv = *(const float4*)(W + (size_t)(k0 + (t>>3))*NCLS + c0 + (t&7)*4);
    __syncthreads();
    Xs[lk+0][lr]=x0.x; Xs[lk+1][lr]=x0.y; Xs[lk+2][lr]=x0.z; Xs[lk+3][lr]=x0.w;
    Xs[lk+0][lr+32]=x1.x; Xs[lk+1][lr+32]=x1.y; Xs[lk+2][lr+32]=x1.z; Xs[lk+3][lr+32]=x1.w;
    *(float4*)&Ws[t>>3][(t&7)*4] = wv;
    __syncthreads();
    #pragma unroll 8
    for (int kk=0;kk<32;kk++){
      float4 av = *(const float4*)&Xs[kk][tm];
      float2 bv = *(const float2*)&Ws[kk][tn];
      acc[0][0] += av.x*bv.x; acc[0][1] += av.x*bv.y;
      acc[1][0] += av.y*bv.x; acc[1][1] += av.y*bv.y;
      acc[2][0] += av.z*bv.x; acc[2][1] += av.z*bv.y;
      acc[3][0] += av.w*bv.x; acc[3][1] += av.w*bv.y;
    }
  }
  float bz0 = bias[c0+tn], bz1 = bias[c0+tn+1];
  #pragma unroll
  for (int i=0;i<4;i++){
    float2 o = make_float2(acc[i][0]+bz0, acc[i][1]+bz1);
    *(float2*)(C + (size_t)(n0+tm+i)*NCLS + c0+tn) = o;
  }
}

// ---------------- per-row top softmax pick: ptop[n] = softmax(TL[n])[targets[n]/225] ----------------
__global__ void k_top_pick(const float* __restrict__ TL, const int* __restrict__ tg,
                           float* __restrict__ ptop){
  int n = blockIdx.x*4 + (threadIdx.x>>6);
  int lane = threadIdx.x&63;
  const float* row = TL + (size_t)n*NCLS;
  float v[4]; float m = -1e30f;
  #pragma unroll
  for (int q=0;q<4;q++){ int c = lane + q*64; v[q] = (c<NCLS)? row[c] : -1e30f; m = fmaxf(m, v[q]); }
  for (int o=32;o;o>>=1) m = fmaxf(m, __shfl_xor(m,o));
  float s = 0.f;
  #pragma unroll
  for (int q=0;q<4;q++){ int c = lane + q*64; if (c<NCLS) s += expf(v[q]-m); }
  for (int o=32;o;o>>=1) s += __shfl_xor(s,o);
  if (lane==0){ int pt = tg[n]/NPC; ptop[n] = expf(row[pt]-m)/s; }
}

// ---------------- class bucketing ----------------
__global__ void k_zero(int* cnt, int* cur){ int t=threadIdx.x; if(t<NCLS){cnt[t]=0; cur[t]=0;} }
__global__ void k_hist(const int* __restrict__ tg, int* cnt){
  int n = blockIdx.x*256+threadIdx.x;
  if (n<NN) atomicAdd(&cnt[tg[n]/NPC],1);
}
__global__ void k_scan(const int* __restrict__ cnt, int* __restrict__ off){
  if (threadIdx.x==0 && blockIdx.x==0){ int a=0; for(int c=0;c<NCLS;c++){ off[c]=a; a+=cnt[c]; } off[NCLS]=a; }
}
__global__ void k_scatter(const int* __restrict__ tg, const int* __restrict__ off,
                          int* cur, int* __restrict__ perm){
  int n = blockIdx.x*256+threadIdx.x;
  if (n<NN){ int c = tg[n]/NPC; int p = atomicAdd(&cur[c],1); perm[off[c]+p] = n; }
}

// ---------------- per-class bottom GEMM + softmax pick + final product ----------------
__global__ __launch_bounds__(256) void k_bot(
    const float* __restrict__ X, const float* __restrict__ botW, const float* __restrict__ botb,
    const int* __restrict__ tg, const int* __restrict__ off, const int* __restrict__ perm,
    const float* __restrict__ ptop, float* __restrict__ outP)
{
  int cls = blockIdx.x;
  int s = off[cls], e = off[cls+1];
  if (s>=e) return;
  __shared__ float xs[16][NH];
  __shared__ float lg[16][228];
  int t = threadIdx.x;
  const float* Wc = botW + (size_t)cls*NH*NPC;
  for (int base=s; base<e; base+=16){
    int nr = min(16, e-base);
    __syncthreads();
    for (int r=0;r<nr;r++){
      int n = perm[base+r];
      *(float4*)&xs[r][t*4] = *(const float4*)(X + (size_t)n*NH + t*4);
    }
    __syncthreads();
    if (t < NPC){
      float acc[16];
      #pragma unroll
      for (int r=0;r<16;r++) acc[r]=0.f;
      for (int k=0;k<NH;k+=2){
        float w0 = Wc[(size_t)k*NPC + t];
        float w1 = Wc[(size_t)(k+1)*NPC + t];
        #pragma unroll
        for (int r=0;r<16;r++){
          float2 x2 = *(const float2*)&xs[r][k];
          acc[r] += x2.x*w0 + x2.y*w1;
        }
      }
      float bb = botb[(size_t)cls*NPC + t];
      for (int r=0;r<nr;r++) lg[r][t] = acc[r] + bb;
    }
    __syncthreads();
    int wv = t>>6, lane = t&63;
    for (int r=wv; r<nr; r+=4){
      float v[4]; float m=-1e30f;
      #pragma unroll
      for (int q=0;q<4;q++){ int c = lane+q*64; v[q] = (c<NPC)? lg[r][c] : -1e30f; m=fmaxf(m,v[q]); }
      for (int o=32;o;o>>=1) m=fmaxf(m,__shfl_xor(m,o));
      float ss=0.f;
      #pragma unroll
      for (int q=0;q<4;q++){ int c = lane+q*64; if (c<NPC) ss += expf(v[q]-m); }
      for (int o=32;o;o>>=1) ss += __shfl_xor(ss,o);
      if (lane==0){
        int n = perm[base+r]; int pb = tg[n]%NPC;
        outP[n] = ptop[n]*expf(lg[r][pb]-m)/ss;
      }
    }
  }
}

extern "C" void kernel_launch(void* const* d_in, const int* in_sizes, int n_in,
                              void* d_out, int out_size, void* d_ws, size_t ws_size,
                              hipStream_t stream)
{
  const int*   ids  = (const int*)d_in[0];
  const int*   tg   = (const int*)d_in[1];
  const float* h0   = (const float*)d_in[2];
  const float* c0   = (const float*)d_in[3];
  const float* embW = (const float*)d_in[4];
  const float* Wih  = (const float*)d_in[5];
  const float* Whh  = (const float*)d_in[6];
  const float* bih  = (const float*)d_in[7];
  const float* bhh  = (const float*)d_in[8];
  const float* topW = (const float*)d_in[9];
  const float* topb = (const float*)d_in[10];
  const float* botW = (const float*)d_in[11];
  const float* botb = (const float*)d_in[12];
  float* out = (float*)d_out;

  float* X  = (float*)d_ws;                    // [NN][NH]
  float* Yb = X  + (size_t)NN*NH;              // [NN][NH]
  float* GT = Yb + (size_t)NN*NH;              // [G4][NN]
  float* hb = GT + (size_t)G4*NN;              // [2][BB][NH]
  float* TL = hb + 2*(size_t)BB*NH;            // [NN][NCLS]
  float* pt = TL + (size_t)NN*NCLS;            // [NN]
  int* cnt  = (int*)(pt + NN);
  int* off  = cnt + NCLS;
  int* cur  = off + NCLS + 1;
  int* perm = cur + NCLS;

  k_embed<<<NN,256,0,stream>>>(ids, embW, X);

  for (int l=0; l<2; l++){
    const float* A   = Wih + (size_t)l*G4*NH;
    const float* Wl  = Whh + (size_t)l*G4*NH;
    const float* bi  = bih + (size_t)l*G4;
    const float* bh  = bhh + (size_t)l*G4;
    const float* Bx  = (l==0)? X : Yb;
    float*       Yo  = (l==0)? Yb : X;
    k_gemm_nt<<<dim3(64,128),256,0,stream>>>(A, Bx, bi, bh, GT, NN);
    const float* h0l = h0 + (size_t)l*BB*NH;
    const float* c0l = c0 + (size_t)l*BB*NH;
    float* hNl = out + NN + (size_t)l*BB*NH;
    float* cNl = out + NN + 2*(size_t)BB*NH + (size_t)l*BB*NH;
    void* args[] = { (void*)&GT, (void*)&Wl, (void*)&h0l, (void*)&c0l,
                     (void*)&hb, (void*)&Yo, (void*)&hNl, (void*)&cNl };
    hipLaunchCooperativeKernel((void*)k_rec, dim3(256), dim3(256), args, 0u, stream);
  }

  // X now holds the layer-1 output sequence [NN][NH]
  k_gemm_top<<<dim3(128,7),256,0,stream>>>(X, topW, topb, TL);
  k_top_pick<<<NN/4,256,0,stream>>>(TL, tg, pt);
  k_zero<<<1,256,0,stream>>>(cnt, cur);
  k_hist<<<NN/256,256,0,stream>>>(tg, cnt);
  k_scan<<<1,1,0,stream>>>(cnt, off);
  k_scatter<<<NN/256,256,0,stream>>>(tg, off, cur, perm);
  k_bot<<<NCLS,256,0,stream>>>(X, botW, botb, tg, off, perm, pt, out);
}